// Round 4
// baseline (686.805 us; speedup 1.0000x reference)
//
#include <hip/hip_runtime.h>
#include <stdint.h>

// Sizes fixed by the problem
#define TPB 512
#define NPTS 4096
#define NBATCH 8
#define NSAMP 1024
#define KK 32
#define CAP 256
#define MLP_BLOCKS 64          // 64 blocks * 512 thr = 32768 points
#define KNN_GROUPS 23
#define KNN_BLOCKS (KNN_GROUPS * NBATCH)   // 184
#define ROWS_PER_G 179                     // ceil(4096/23)
#define GRID1 (NBATCH + MLP_BLOCKS + KNN_BLOCKS)  // 256 blocks -> 1 per CU, all resident
#define DYN_LDS 111616

__launch_bounds__(TPB, 2)
__global__ void k1(const float* __restrict__ xyz, const float* __restrict__ feat,
                   const float* __restrict__ w1, const float* __restrict__ b1,
                   const float* __restrict__ w2, const float* __restrict__ b2,
                   const float* __restrict__ w3, const float* __restrict__ b3,
                   float* __restrict__ dout, float* __restrict__ ws_m,
                   unsigned short* __restrict__ ws_idx)
{
    extern __shared__ float S[];
    const int tid = threadIdx.x;
    const int blk = blockIdx.x;

    if (blk < NBATCH) {
        // ------------------------- FPS (one block per batch) -------------------------
        // All 512 threads; thread t owns points [t*8, t*8+8) (blocked -> lane order
        // == index order, so prefer-left/lowest-lane tie-breaks replicate np.argmax).
        // No indices anywhere: candidates carry (d2, x, y, z); the winner's coords
        // become the next query directly (removes the dependent pts4[far] load).
        const int b = blk;
        float4* pts4 = (float4*)S;
        const float* xb = xyz + (size_t)b * NPTS * 3;
        for (int j = tid; j < NPTS; j += TPB)
            pts4[j] = make_float4(xb[j*3], xb[j*3+1], xb[j*3+2], 0.f);
        __syncthreads();
        float4* cand = (float4*)(S + 16384);   // 2 buffers x 8 entries {d2, x, y, z}
        const int lane = tid & 63, w = tid >> 6;
        const int base = tid * 8;
        float4 q_;
#define LDP(i) q_ = pts4[base + i]; \
               float px##i = q_.x, py##i = q_.y, pz##i = q_.z, dd##i = 1e10f;
        LDP(0) LDP(1) LDP(2) LDP(3) LDP(4) LDP(5) LDP(6) LDP(7)
#undef LDP
        // Launder: make coords opaque so the compiler CANNOT rematerialize them
        // from LDS each step (R3: VGPR=60 proved it was re-loading). Forces VGPRs.
        asm volatile("" : "+v"(px0),"+v"(py0),"+v"(pz0),"+v"(px1),"+v"(py1),"+v"(pz1),
                          "+v"(px2),"+v"(py2),"+v"(pz2),"+v"(px3),"+v"(py3),"+v"(pz3));
        asm volatile("" : "+v"(px4),"+v"(py4),"+v"(pz4),"+v"(px5),"+v"(py5),"+v"(pz5),
                          "+v"(px6),"+v"(py6),"+v"(pz6),"+v"(px7),"+v"(py7),"+v"(pz7));
        float4 f0 = pts4[0];
        float fx = f0.x, fy = f0.y, fz = f0.z;
        float* ox = dout + (size_t)b * NSAMP * 3;
        // select(b1>b0 ? right : left): strict > keeps the LEFT (lower index) on ties
#define NODE(bo,xo,yo,zo, b0,x0,y0,z0, b1,x1,y1,z1) \
        bool c##bo = (b1) > (b0); \
        float bo = c##bo ? (b1) : (b0); float xo = c##bo ? (x1) : (x0); \
        float yo = c##bo ? (y1) : (y0); float zo = c##bo ? (z1) : (z0);
        for (int step = 0; step < NSAMP; ++step) {
            if (tid == 0) { ox[step*3] = fx; ox[step*3+1] = fy; ox[step*3+2] = fz; }
            // EXACT numpy-f32: no fma, sum = (x2+y2)+z2. All d2 >= +0 (no NaN/-0),
            // so float compares define the same total order as the reference.
#define UPD(i) { float dx = __fsub_rn(px##i, fx); \
                 float dy = __fsub_rn(py##i, fy); \
                 float dz = __fsub_rn(pz##i, fz); \
                 float d  = __fadd_rn(__fadd_rn(__fmul_rn(dx,dx), __fmul_rn(dy,dy)), \
                                      __fmul_rn(dz,dz)); \
                 dd##i = fminf(dd##i, d); }
            UPD(0) UPD(1) UPD(2) UPD(3) UPD(4) UPD(5) UPD(6) UPD(7)
#undef UPD
            // in-lane argmax tree (depth 3), payload = coords
            NODE(b01,x01,y01,z01, dd0,px0,py0,pz0, dd1,px1,py1,pz1)
            NODE(b23,x23,y23,z23, dd2,px2,py2,pz2, dd3,px3,py3,pz3)
            NODE(b45,x45,y45,z45, dd4,px4,py4,pz4, dd5,px5,py5,pz5)
            NODE(b67,x67,y67,z67, dd6,px6,py6,pz6, dd7,px7,py7,pz7)
            NODE(b03,x03,y03,z03, b01,x01,y01,z01, b23,x23,y23,z23)
            NODE(b47,x47,y47,z47, b45,x45,y45,z45, b67,x67,y67,z67)
            NODE(lb,lx,ly,lz,     b03,x03,y03,z03, b47,x47,y47,z47)
            // wave max via DPP (6 dependent v_max), then lowest matching lane
            float wm = lb;
#define DSTEP(ctrl) { float t_ = __int_as_float(__builtin_amdgcn_update_dpp( \
                          __float_as_int(wm), __float_as_int(wm), ctrl, 0xF, 0xF, false)); \
                      wm = fmaxf(wm, t_); }
            DSTEP(0xB1)   // quad_perm xor1
            DSTEP(0x4E)   // quad_perm xor2
            DSTEP(0x141)  // row_half_mirror
            DSTEP(0x140)  // row_mirror
            DSTEP(0x142)  // row_bcast15
            DSTEP(0x143)  // row_bcast31
#undef DSTEP
            float wmax = __int_as_float(__builtin_amdgcn_readlane(__float_as_int(wm), 63));
            unsigned long long mm = __ballot(lb == wmax);
            int fl = (int)__ffsll(mm) - 1;
            if (lane == fl) cand[(step & 1)*8 + w] = make_float4(lb, lx, ly, lz);
            __syncthreads();
            // cross-wave combine: 8 broadcast b128 reads + depth-3 tree
            const float4* cc = cand + (step & 1)*8;
            float4 e0 = cc[0], e1 = cc[1], e2 = cc[2], e3 = cc[3];
            float4 e4 = cc[4], e5 = cc[5], e6 = cc[6], e7 = cc[7];
            NODE(g01,u01,v01,s01, e0.x,e0.y,e0.z,e0.w, e1.x,e1.y,e1.z,e1.w)
            NODE(g23,u23,v23,s23, e2.x,e2.y,e2.z,e2.w, e3.x,e3.y,e3.z,e3.w)
            NODE(g45,u45,v45,s45, e4.x,e4.y,e4.z,e4.w, e5.x,e5.y,e5.z,e5.w)
            NODE(g67,u67,v67,s67, e6.x,e6.y,e6.z,e6.w, e7.x,e7.y,e7.z,e7.w)
            NODE(g03,u03,v03,s03, g01,u01,v01,s01, g23,u23,v23,s23)
            NODE(g47,u47,v47,s47, g45,u45,v45,s45, g67,u67,v67,s67)
            NODE(gf,uf,vf,sf,     g03,u03,v03,s03, g47,u47,v47,s47)
            fx = uf; fy = vf; fz = sf;
        }
#undef NODE
    } else if (blk < NBATCH + MLP_BLOCKS) {
        // ------------------------- per-point MLP -> m[b,j] ---------------------------
        for (int i = tid; i < 1216; i += TPB) S[i] = w1[i];
        for (int i = tid; i < 64; i += TPB) S[1216 + i] = b1[i];
        float2* w2i = (float2*)(S + 1280);
        for (int i = tid; i < 64*64; i += TPB) {
            int k = i >> 6, l = i & 63;
            w2i[i] = make_float2(w2[k*128 + l], w2[k*128 + 64 + l]);
        }
        float2* b2i = (float2*)(S + 9472);
        for (int i = tid; i < 64; i += TPB) b2i[i] = make_float2(b2[i], b2[i + 64]);
        float2* w3i = (float2*)(S + 9600);
        for (int i = tid; i < 128*64; i += TPB) {
            int k = i >> 6, l = i & 63;
            w3i[i] = make_float2(w3[k*128 + l], w3[k*128 + 64 + l]);
        }
        float2* b3i = (float2*)(S + 25984);
        for (int i = tid; i < 64; i += TPB) b3i[i] = make_float2(b3[i], b3[i + 64]);
        __syncthreads();
        const int w = tid >> 6, lane = tid & 63;
        float* gs  = S + 26112 + w*224;
        float* h1s = gs + 32;
        float* h2s = gs + 96;
        const int pbase = (blk - NBATCH) * TPB + w*64;
        for (int i = 0; i < 64; ++i) {
            int p = pbase + i;
            int b = p >> 12, j = p & 4095;
            if (lane < 19) {
                float v = (lane < 3) ? xyz[((size_t)(b*NPTS + j))*3 + lane]
                                     : feat[((size_t)(b*NPTS + j))*16 + (lane - 3)];
                gs[lane] = v;
            }
            __syncthreads();
            float acc = S[1216 + lane];
            #pragma unroll
            for (int c = 0; c < 19; ++c) acc = fmaf(gs[c], S[c*64 + lane], acc);
            h1s[lane] = fmaxf(acc, 0.f);
            __syncthreads();
            float2 a2 = b2i[lane];
            #pragma unroll 4
            for (int k = 0; k < 64; ++k) {
                float a = h1s[k];
                float2 wv = w2i[k*64 + lane];
                a2.x = fmaf(a, wv.x, a2.x);
                a2.y = fmaf(a, wv.y, a2.y);
            }
            h2s[lane] = fmaxf(a2.x, 0.f);
            h2s[64 + lane] = fmaxf(a2.y, 0.f);
            __syncthreads();
            float2 a3 = b3i[lane];
            #pragma unroll 4
            for (int k = 0; k < 128; ++k) {
                float a = h2s[k];
                float2 wv = w3i[k*64 + lane];
                a3.x = fmaf(a, wv.x, a3.x);
                a3.y = fmaf(a, wv.y, a3.y);
            }
            float mm = fmaxf(a3.x, a3.y);
            #pragma unroll
            for (int off = 32; off; off >>= 1) mm = fmaxf(mm, __shfl_xor(mm, off));
            if (lane == 0) ws_m[p] = mm;
        }
    } else {
        // ------------------------- exact KNN top-32 per row --------------------------
        const int bb = blk - (NBATCH + MLP_BLOCKS);
        const int b = bb & 7, g = bb >> 3;
        float4* pts4 = (float4*)S;
        const float* xb = xyz + (size_t)b * NPTS * 3;
        for (int j = tid; j < NPTS; j += TPB)
            pts4[j] = make_float4(xb[j*3], xb[j*3+1], xb[j*3+2], 0.f);
        __syncthreads();
        const int w = tid >> 6, lane = tid & 63;
        unsigned long long* list = (unsigned long long*)(S + 16384) + (size_t)w * CAP;
        const unsigned long long laneml = (1ull << lane) - 1ull;
        int rend = (g + 1) * ROWS_PER_G; if (rend > NPTS) rend = NPTS;
        for (int r = g*ROWS_PER_G + w; r < rend; r += 8) {
            float4 q = pts4[r];
            float T = 0.0315f, Tlo = 0.f, Thi = 0.f;
            int hasLo = 0, hasHi = 0, cnt = 0;
            for (int iter = 0; iter < 24; ++iter) {
                cnt = 0;
                for (int t = 0; t < 64; ++t) {
                    int j = t*64 + lane;
                    float4 p = pts4[j];
                    float dx = __fsub_rn(p.x, q.x);
                    float dy = __fsub_rn(p.y, q.y);
                    float dz = __fsub_rn(p.z, q.z);
                    float d2 = __fadd_rn(__fadd_rn(__fmul_rn(dx,dx), __fmul_rn(dy,dy)),
                                         __fmul_rn(dz,dz));
                    bool pred = d2 <= T;
                    unsigned long long mask = __ballot(pred);
                    if (pred) {
                        int pos = cnt + __popcll(mask & laneml);
                        if (pos < CAP)
                            list[pos] = ((unsigned long long)__float_as_uint(d2) << 32) | (unsigned)j;
                    }
                    cnt += __popcll(mask);
                }
                if (cnt >= KK && cnt <= CAP) break;
                if (cnt < KK) { Tlo = T; hasLo = 1; } else { Thi = T; hasHi = 1; }
                if (hasLo && hasHi) T = sqrtf(Tlo * Thi);
                else if (cnt < KK) T *= 3.0f;
                else T *= 0.45f;
            }
            if (cnt > CAP) cnt = CAP;
            __builtin_amdgcn_wave_barrier();
            // exact rank among keys (d2bits<<32)|idx: rank<32 == top_k slot
            unsigned long long kc[4]; unsigned rk[4];
            #pragma unroll
            for (int c = 0; c < 4; ++c) {
                int sl = c*64 + lane;
                kc[c] = (sl < cnt) ? list[sl] : ~0ull;
                rk[c] = 0u;
            }
            for (int i = 0; i < cnt; ++i) {
                unsigned long long kb = list[i];
                #pragma unroll
                for (int c = 0; c < 4; ++c) rk[c] += (kb < kc[c]) ? 1u : 0u;
            }
            unsigned short* orow = ws_idx + ((size_t)(b*NPTS + r)) * KK;
            #pragma unroll
            for (int c = 0; c < 4; ++c) {
                int sl = c*64 + lane;
                if (sl < cnt && rk[c] < KK)
                    orow[rk[c]] = (unsigned short)(kc[c] & 0xffffull);
            }
        }
    }
}

__global__ void k2(const unsigned short* __restrict__ idx16, const float* __restrict__ m,
                   float* __restrict__ outf)
{
    int t = blockIdx.x * 512 + threadIdx.x;   // 2048*512 = 1048576 = 8*4096*32
    int b = t >> 17;                          // 4096*32 = 131072 per batch
    outf[t] = m[b*4096 + (int)idx16[t]];
}

extern "C" void kernel_launch(void* const* d_in, const int* in_sizes, int n_in,
                              void* d_out, int out_size, void* d_ws, size_t ws_size,
                              hipStream_t stream)
{
    const float* xyz  = (const float*)d_in[0];
    const float* feat = (const float*)d_in[1];
    const float* w1   = (const float*)d_in[2];
    const float* b1   = (const float*)d_in[3];
    const float* w2   = (const float*)d_in[4];
    const float* b2   = (const float*)d_in[5];
    const float* w3   = (const float*)d_in[6];
    const float* b3   = (const float*)d_in[7];
    float* dout = (float*)d_out;
    float* ws_m = (float*)d_ws;                                  // 32768 f32
    unsigned short* ws_idx = (unsigned short*)((char*)d_ws + 131072);  // 1M u16

    hipFuncSetAttribute((const void*)k1, hipFuncAttributeMaxDynamicSharedMemorySize, DYN_LDS);

    hipLaunchKernelGGL(k1, dim3(GRID1), dim3(TPB), DYN_LDS, stream,
                       xyz, feat, w1, b1, w2, b2, w3, b3, dout, ws_m, ws_idx);
    hipLaunchKernelGGL(k2, dim3(2048), dim3(512), 0, stream,
                       ws_idx, ws_m, dout + 24576);
}